// Round 8
// baseline (210.480 us; speedup 1.0000x reference)
//
#include <hip/hip_runtime.h>
#include <hip/hip_bf16.h>

// Problem constants
#define B_   2
#define S_   2048
#define DIM_ 2048
#define NH   16
#define NKV  4
#define HD   128
#define QKVN 3072   // fused projection width: 2048 (Q) + 512 (K) + 512 (V)

typedef __attribute__((ext_vector_type(8)))  short  sv8;   // 8 x bf16 (MFMA operand)
typedef __attribute__((ext_vector_type(8)))  ushort usv8;
typedef __attribute__((ext_vector_type(4)))  float  fv4;
typedef __attribute__((ext_vector_type(16))) float  fv16;

__device__ __forceinline__ float fast_exp2(float x) {
  return __builtin_amdgcn_exp2f(x);   // v_exp_f32 (base-2)
}

__device__ __forceinline__ ushort f2bf(float f) {
  __hip_bfloat16 h = __float2bfloat16(f);
  union { __hip_bfloat16 h; ushort u; } c; c.h = h; return c.u;
}
__device__ __forceinline__ float bf2f(ushort u) {
  union { unsigned int i; float f; } c; c.i = ((unsigned)u) << 16; return c.f;
}

// pack two f32 -> two bf16 in one u32 (src0 -> low 16, src1 -> high 16)
__device__ __forceinline__ unsigned int cvtpk(float lo, float hi) {
  unsigned int r;
  asm("v_cvt_pk_bf16_f32 %0, %1, %2" : "=v"(r) : "v"(lo), "v"(hi));
  return r;
}
// exchange with partner lane (lane ^ 32)
__device__ __forceinline__ unsigned int xhalf(unsigned int x) {
  return (unsigned int)__shfl_xor((int)x, 32, 64);
}

// tree reductions over a 16-vector (depth 5, ILP-friendly)
__device__ __forceinline__ float tmax16(const fv16& v) {
  float a = fmaxf(fmaxf(v[0], v[1]),  fmaxf(v[2], v[3]));
  float b = fmaxf(fmaxf(v[4], v[5]),  fmaxf(v[6], v[7]));
  float c = fmaxf(fmaxf(v[8], v[9]),  fmaxf(v[10], v[11]));
  float d = fmaxf(fmaxf(v[12], v[13]), fmaxf(v[14], v[15]));
  return fmaxf(fmaxf(a, b), fmaxf(c, d));
}
__device__ __forceinline__ float tsum16(const fv16& v) {
  float a = (v[0] + v[1]) + (v[2] + v[3]);
  float b = (v[4] + v[5]) + (v[6] + v[7]);
  float c = (v[8] + v[9]) + (v[10] + v[11]);
  float d = (v[12] + v[13]) + (v[14] + v[15]);
  return (a + b) + (c + d);
}

// async global->LDS, 16B per lane; LDS dest is wave-uniform base (HW adds lane*16).
__device__ __forceinline__ void async16(const void* g, void* l) {
  __builtin_amdgcn_global_load_lds(
      (const __attribute__((address_space(1))) unsigned int*)g,
      (__attribute__((address_space(3))) unsigned int*)l, 16, 0, 0);
}

// ---------------- f32 -> bf16 convert ----------------
__global__ void cvt_kernel(const float* __restrict__ in, ushort* __restrict__ out, int n) {
  int i = (blockIdx.x * 256 + threadIdx.x) * 4;
  if (i >= n) return;
  fv4 v = *(const fv4*)(in + i);
  ushort4 o;
  o.x = f2bf(v[0]); o.y = f2bf(v[1]); o.z = f2bf(v[2]); o.w = f2bf(v[3]);
  *(ushort4*)(out + i) = o;
}

// ---------------- RoPE (+ scale), relayout to (B, heads, S, HD) ----------------
__global__ void rope_kernel(const ushort* __restrict__ raw, const float* __restrict__ fc,
                            const float* __restrict__ fs, ushort* __restrict__ out,
                            int heads, int rowstride, float scale) {
  int t = blockIdx.x * 256 + threadIdx.x;   // B*S*heads*16 threads, 8 elems each
  int grp = t & 15;
  int h   = (t >> 4) % heads;
  int s   = ((t >> 4) / heads) % S_;
  int b   = t / (16 * heads * S_);
  const ushort* src = raw + (size_t)(b * S_ + s) * rowstride + h * HD + grp * 8;
  sv8 v = *(const sv8*)src;
  fv4 c  = *(const fv4*)(fc + s * 64 + grp * 4);
  fv4 sn = *(const fv4*)(fs + s * 64 + grp * 4);
  sv8 o;
#pragma unroll
  for (int p = 0; p < 4; ++p) {
    float re = bf2f((ushort)v[2 * p]);
    float im = bf2f((ushort)v[2 * p + 1]);
    float orr = (re * c[p] - im * sn[p]) * scale;
    float oi  = (re * sn[p] + im * c[p]) * scale;
    o[2 * p]     = (short)f2bf(orr);
    o[2 * p + 1] = (short)f2bf(oi);
  }
  ushort* dst = out + ((size_t)(b * heads + h) * S_ + s) * HD + grp * 8;
  *(sv8*)dst = o;
}

// ---------------- V transpose: rows of fused qkv -> (B,KVH,HD,S) ----------------
__global__ __launch_bounds__(256) void vtrans_kernel(const ushort* __restrict__ vraw,
                                                     ushort* __restrict__ vt, int rowstride) {
  __shared__ ushort tile[128][136];
  int blk = blockIdx.x;            // (b*NKV+kv)*16 + st
  int st  = blk & 15;
  int kvb = blk >> 4;
  int kv  = kvb & 3;
  int b   = kvb >> 2;
  int s0  = st << 7;
#pragma unroll
  for (int it = 0; it < 8; ++it) {
    int t = it * 256 + threadIdx.x;
    int srow = t >> 4;
    int d8 = (t & 15) * 8;
    usv8 v = *(const usv8*)(vraw + (size_t)(b * S_ + s0 + srow) * rowstride + kv * HD + d8);
#pragma unroll
    for (int j = 0; j < 8; ++j) tile[d8 + j][srow] = v[j];
  }
  __syncthreads();
#pragma unroll
  for (int it = 0; it < 8; ++it) {
    int t = it * 256 + threadIdx.x;
    int d = t >> 4;
    int s8 = (t & 15) * 8;
    usv8 o;
#pragma unroll
    for (int j = 0; j < 8; ++j) o[j] = tile[d][s8 + j];
    *(usv8*)(vt + ((size_t)(b * NKV + kv) * HD + d) * S_ + s0 + s8) = o;
  }
}

// ---------------- 8-phase 256x256 GEMM: C[M,N] = A[M,K]*B[N,K]^T (T2+T3+T4+T5) ------
// 512 thr = 8 waves (2M x 4N), per-wave 128x64 out. BK=64. LDS 128KB:
// [buf][A0,A1,B0,B1] 16KB parts ([128 rows][128B], (row&7)<<4 XOR swizzle).
// Per K-tile, 4 phases; staging (T+2) parts placed AFTER last reads of the
// region (B at P3, A at P4); counted vmcnt(8) = 2 loads/HT x 4 HT in flight.
template <typename OutT>
__global__ __launch_bounds__(512, 2) void gemm256(const ushort* __restrict__ A,
                                                  const ushort* __restrict__ Bm,
                                                  OutT* __restrict__ C,
                                                  int M, int N, int K) {
  __shared__ __align__(16) ushort SM[65536];   // 128KB
  int nb = N >> 8;
  int bx = blockIdx.x % nb, by = blockIdx.x / nb;
  int m0 = by << 8, n0 = bx << 8;
  int tid = threadIdx.x;
  int lane = tid & 63, w = tid >> 6;
  int l15 = lane & 15, lg = lane >> 4;
  int wm = (w >> 2) * 128;          // wave M offset in tile
  int wn = (w & 3) * 64;            // wave N offset
  int pA = (w >> 2);                // A part 0/1
  int pB = 2 + ((w & 3) >> 1);      // B part 2/3
  int brow0 = (w & 1) * 64;         // local B row base within part

  // staging sources (per-thread, pre-swizzled column)
  int srow = tid >> 3;
  int cb   = ((tid & 7) * 16) ^ ((srow & 7) << 4);
  const ushort* sA0 = A  + (size_t)(m0 + srow) * K + (cb >> 1);
  const ushort* sB0 = Bm + (size_t)(n0 + srow) * K + (cb >> 1);
  const ushort* srcs[4] = { sA0, sA0 + (size_t)128 * K, sB0, sB0 + (size_t)128 * K };
  size_t rstep = (size_t)64 * K;    // second-load row offset (rows +64, same swizzle)

  int nkt = K >> 6;

  auto STG = [&](int part, int t, int db) {
    ushort* d0 = SM + db * 32768 + part * 8192 + (w << 9);   // bytes: db*64KB + part*16KB + w*1KB
    const ushort* s0 = srcs[part] + t * 64;
    async16(s0, d0);
    async16(s0 + rstep, d0 + 4096);
  };

  fv4 acc[8][4] = {};
  sv8 a[4][2], b[2][2], b2[2][2];

  // prologue: tiles 0 and 1 fully staged
#pragma unroll
  for (int p = 0; p < 4; ++p) STG(p, 0, 0);
  {
    int t1 = 1 < nkt ? 1 : 0;
#pragma unroll
    for (int p = 0; p < 4; ++p) STG(p, t1, 1);
  }
  asm volatile("s_waitcnt vmcnt(8)");
  __builtin_amdgcn_s_barrier();

  for (int t = 0; t < nkt; ++t) {
    int db = t & 1;
    int t2 = t + 2 < nkt ? t + 2 : nkt - 1;
    const char* Ab = (const char*)SM + db * 65536 + pA * 16384;
    const char* Bb = (const char*)SM + db * 65536 + pB * 16384;

    // ---- P1: ds_read A m0-3 (8), B j0-1 (4); MFMA Q(m0-3 x j0-1) ----
#pragma unroll
    for (int m = 0; m < 4; ++m)
#pragma unroll
      for (int kk = 0; kk < 2; ++kk) {
        int row = m * 16 + l15;
        a[m][kk] = *(const sv8*)(Ab + row * 128 + ((kk * 64 + lg * 16) ^ ((row & 7) << 4)));
      }
#pragma unroll
    for (int j = 0; j < 2; ++j)
#pragma unroll
      for (int kk = 0; kk < 2; ++kk) {
        int row = brow0 + j * 16 + l15;
        b[j][kk] = *(const sv8*)(Bb + row * 128 + ((kk * 64 + lg * 16) ^ ((row & 7) << 4)));
      }
    __builtin_amdgcn_s_barrier();
    asm volatile("s_waitcnt lgkmcnt(0)");
    __builtin_amdgcn_s_setprio(1);
#pragma unroll
    for (int m = 0; m < 4; ++m)
#pragma unroll
      for (int j = 0; j < 2; ++j)
#pragma unroll
        for (int kk = 0; kk < 2; ++kk)
          acc[m][j] = __builtin_amdgcn_mfma_f32_16x16x32_bf16(a[m][kk], b[j][kk], acc[m][j], 0, 0, 0);
    __builtin_amdgcn_s_setprio(0);
    __builtin_amdgcn_s_barrier();

    // ---- P2: ds_read B j2-3 (4); MFMA Q(m0-3 x j2-3) ----
#pragma unroll
    for (int j = 0; j < 2; ++j)
#pragma unroll
      for (int kk = 0; kk < 2; ++kk) {
        int row = brow0 + (j + 2) * 16 + l15;
        b2[j][kk] = *(const sv8*)(Bb + row * 128 + ((kk * 64 + lg * 16) ^ ((row & 7) << 4)));
      }
    __builtin_amdgcn_s_barrier();
    asm volatile("s_waitcnt lgkmcnt(0)");
    __builtin_amdgcn_s_setprio(1);
#pragma unroll
    for (int m = 0; m < 4; ++m)
#pragma unroll
      for (int j = 0; j < 2; ++j)
#pragma unroll
        for (int kk = 0; kk < 2; ++kk)
          acc[m][j + 2] = __builtin_amdgcn_mfma_f32_16x16x32_bf16(a[m][kk], b2[j][kk], acc[m][j + 2], 0, 0, 0);
    __builtin_amdgcn_s_setprio(0);
    __builtin_amdgcn_s_barrier();

    // ---- P3: ds_read A m4-7 (8, overwrite a); stage (T+2)B0,B1; MFMA Q(m4-7 x j2-3) ----
#pragma unroll
    for (int m = 0; m < 4; ++m)
#pragma unroll
      for (int kk = 0; kk < 2; ++kk) {
        int row = 64 + m * 16 + l15;
        a[m][kk] = *(const sv8*)(Ab + row * 128 + ((kk * 64 + lg * 16) ^ ((row & 7) << 4)));
      }
    STG(2, t2, db);
    STG(3, t2, db);
    __builtin_amdgcn_s_barrier();
    asm volatile("s_waitcnt lgkmcnt(0)");
    __builtin_amdgcn_s_setprio(1);
#pragma unroll
    for (int m = 0; m < 4; ++m)
#pragma unroll
      for (int j = 0; j < 2; ++j)
#pragma unroll
        for (int kk = 0; kk < 2; ++kk)
          acc[m + 4][j + 2] = __builtin_amdgcn_mfma_f32_16x16x32_bf16(a[m][kk], b2[j][kk], acc[m + 4][j + 2], 0, 0, 0);
    __builtin_amdgcn_s_setprio(0);
    __builtin_amdgcn_s_barrier();

    // ---- P4: stage (T+2)A0,A1; vmcnt(8) -> tile T+1 landed; MFMA Q(m4-7 x j0-1) ----
    STG(0, t2, db);
    STG(1, t2, db);
    asm volatile("s_waitcnt vmcnt(8)");
    __builtin_amdgcn_s_barrier();
    __builtin_amdgcn_s_setprio(1);
#pragma unroll
    for (int m = 0; m < 4; ++m)
#pragma unroll
      for (int j = 0; j < 2; ++j)
#pragma unroll
        for (int kk = 0; kk < 2; ++kk)
          acc[m + 4][j] = __builtin_amdgcn_mfma_f32_16x16x32_bf16(a[m][kk], b[j][kk], acc[m + 4][j], 0, 0, 0);
    __builtin_amdgcn_s_setprio(0);
    __builtin_amdgcn_s_barrier();
  }

  asm volatile("s_waitcnt vmcnt(0)");
#pragma unroll
  for (int m = 0; m < 8; ++m)
#pragma unroll
    for (int j = 0; j < 4; ++j)
#pragma unroll
      for (int r = 0; r < 4; ++r) {
        int row = m0 + wm + m * 16 + lg * 4 + r;
        int col = n0 + wn + j * 16 + l15;
        if constexpr (sizeof(OutT) == 2) C[(size_t)row * N + col] = (OutT)f2bf(acc[m][j][r]);
        else                             C[(size_t)row * N + col] = (OutT)acc[m][j][r];
      }
}

// ---------------- Flash attention (causal, GQA) ---------------- (unchanged)
__global__ __launch_bounds__(512, 2) void attn_kernel(const ushort* __restrict__ Q,
                                                      const ushort* __restrict__ Kr,
                                                      const ushort* __restrict__ Vt,
                                                      ushort* __restrict__ O) {
  __shared__ __align__(16) ushort SMEM[65536];   // 128KB

  int blk = blockIdx.x;
  int bh  = blk & 31;
  int pr  = blk >> 5;
  int h   = bh & 15;
  int b   = bh >> 4;
  int kv  = h >> 2;
  int lane = threadIdx.x & 63, w = threadIdx.x >> 6;
  int wg = w & 3, Hf = w >> 2;
  int l31 = lane & 31, hh = lane >> 5;

  const ushort* Qbase = Q  + (size_t)(b * NH  + h ) * S_ * HD;
  const ushort* Kbase = Kr + (size_t)(b * NKV + kv) * S_ * HD;
  const ushort* Vbase = Vt + (size_t)(b * NKV + kv) * HD * S_;

  const ushort* kSrc[4]; ushort* kDst[2][4];
  const ushort* vSrc[4]; ushort* vDst[2][4];
#pragma unroll
  for (int it = 0; it < 4; ++it) {
    int lin = it * 4096 + wg * 1024 + lane * 16;
    { int row = lin >> 8; int cbv = (lin & 255) ^ ((row & 7) << 4);
      kSrc[it] = Kbase + (size_t)row * HD + (cbv >> 1); }
    { int row = lin >> 7; int cbv = (lin & 127) ^ ((row & 7) << 4);
      vSrc[it] = Vbase + (size_t)row * S_ + (cbv >> 1); }
#pragma unroll
    for (int buf = 0; buf < 2; ++buf) {
      kDst[buf][it] = SMEM + Hf * 16384 + buf * 8192 + ((it * 4096 + wg * 1024) >> 1);
      vDst[buf][it] = SMEM + 32768 + Hf * 16384 + buf * 8192 + ((it * 4096 + wg * 1024) >> 1);
    }
  }

  float* cML = (float*)SMEM;
  float* cO  = (float*)SMEM + 512;

  for (int pass = 0; pass < 2; ++pass) {
    int qt = pass ? (15 - pr) : pr;
    int q0 = qt << 7;
    int qrow_w = q0 + wg * 32;
    int myq    = qrow_w + l31;
    int nj     = qt + 1;
    int ktbase = Hf * nj;

    sv8 qf[8];
#pragma unroll
    for (int kk = 0; kk < 8; ++kk)
      qf[kk] = *(const sv8*)(Qbase + (size_t)myq * HD + kk * 16 + hh * 8);

    fv16 oacc[4] = {};
    float mrun = -1e30f, lrun = 0.f;

    {
      size_t k0 = (size_t)ktbase << 6;
#pragma unroll
      for (int it = 0; it < 4; ++it) async16(kSrc[it] + k0 * HD, kDst[0][it]);
#pragma unroll
      for (int it = 0; it < 4; ++it) async16(vSrc[it] + k0,      vDst[0][it]);
    }

    for (int j = 0; j < nj; ++j) {
      int cur = j & 1, nxt = cur ^ 1;
      __syncthreads();
      if (j + 1 < nj) {
        size_t k0n = (size_t)(ktbase + j + 1) << 6;
#pragma unroll
        for (int it = 0; it < 4; ++it) async16(kSrc[it] + k0n * HD, kDst[nxt][it]);
#pragma unroll
        for (int it = 0; it < 4; ++it) async16(vSrc[it] + k0n,      vDst[nxt][it]);
      }
      const char* KsC = (const char*)(SMEM + Hf * 16384 + cur * 8192);
      const char* VsC = (const char*)(SMEM + 32768 + Hf * 16384 + cur * 8192);
      int k0 = (ktbase + j) << 6;

      fv16 sacc[2] = {};
      __builtin_amdgcn_s_setprio(1);
#pragma unroll
      for (int kk = 0; kk < 8; ++kk) {
        int cbq = kk * 32 + hh * 16;
        int r0 = l31, r1 = 32 + l31;
        sv8 kf0 = *(const sv8*)(KsC + r0 * 256 + (cbq ^ ((r0 & 7) << 4)));
        sv8 kf1 = *(const sv8*)(KsC + r1 * 256 + (cbq ^ ((r1 & 7) << 4)));
        sacc[0] = __builtin_amdgcn_mfma_f32_32x32x16_bf16(kf0, qf[kk], sacc[0], 0, 0, 0);
        sacc[1] = __builtin_amdgcn_mfma_f32_32x32x16_bf16(kf1, qf[kk], sacc[1], 0, 0, 0);
      }
      __builtin_amdgcn_s_setprio(0);

      if (k0 + 63 > qrow_w) {
        int thr = myq - k0 - 4 * hh;
#pragma unroll
        for (int t = 0; t < 2; ++t)
#pragma unroll
          for (int r = 0; r < 16; ++r) {
            int kp = t * 32 + (r & 3) + 8 * (r >> 2);
            if (kp > thr) sacc[t][r] = -1e38f;
          }
      }

      float tmax = fmaxf(tmax16(sacc[0]), tmax16(sacc[1]));
      tmax = fmaxf(tmax, __shfl_xor(tmax, 32, 64));

      if (__any(tmax > mrun + 8.0f)) {
        float mnew = fmaxf(mrun, tmax);
        float esc  = fast_exp2(mrun - mnew);
        lrun *= esc;
        float er[16];
#pragma unroll
        for (int r = 0; r < 16; ++r) er[r] = __shfl(esc, (r & 3) + 8 * (r >> 2) + 4 * hh, 64);
#pragma unroll
        for (int d0 = 0; d0 < 4; ++d0)
#pragma unroll
          for (int r = 0; r < 16; ++r) oacc[d0][r] *= er[r];
        mrun = mnew;
      }

#pragma unroll
      for (int t = 0; t < 2; ++t)
#pragma unroll
        for (int r = 0; r < 16; ++r) sacc[t][r] = fast_exp2(sacc[t][r] - mrun);
      float psum = tsum16(sacc[0]) + tsum16(sacc[1]);
      psum += __shfl_xor(psum, 32, 64);
      lrun += psum;

      union Frag { unsigned int u[4]; sv8 v; } pa[4];
#pragma unroll
      for (int t = 0; t < 2; ++t)
#pragma unroll
        for (int half = 0; half < 2; ++half) {
          int cbq = half * 8;
          unsigned int a0 = cvtpk(sacc[t][cbq + 0], sacc[t][cbq + 1]);
          unsigned int a1 = cvtpk(sacc[t][cbq + 2], sacc[t][cbq + 3]);
          unsigned int b0 = cvtpk(sacc[t][cbq + 4], sacc[t][cbq + 5]);
          unsigned int b1 = cvtpk(sacc[t][cbq + 6], sacc[t][cbq + 7]);
          unsigned int a0p = xhalf(a0), a1p = xhalf(a1);
          unsigned int b0p = xhalf(b0), b1p = xhalf(b1);
          pa[2 * t + half].u[0] = hh ? b0p : a0;
          pa[2 * t + half].u[1] = hh ? b1p : a1;
          pa[2 * t + half].u[2] = hh ? b0  : a0p;
          pa[2 * t + half].u[3] = hh ? b1  : a1p;
        }

      __builtin_amdgcn_s_setprio(1);
#pragma unroll
      for (int ks = 0; ks < 4; ++ks) {
        int cbq = ks * 32 + hh * 16;
#pragma unroll
        for (int d0 = 0; d0 < 4; ++d0) {
          int row = d0 * 32 + l31;
          sv8 vf = *(const sv8*)(VsC + row * 128 + (cbq ^ ((row & 7) << 4)));
          oacc[d0] = __builtin_amdgcn_mfma_f32_32x32x16_bf16(pa[ks].v, vf, oacc[d0], 0, 0, 0);
        }
      }
      __builtin_amdgcn_s_setprio(0);
    }

    __syncthreads();
    if (Hf) {
      int base = wg * 64 + lane;
      cML[base * 2]     = mrun;
      cML[base * 2 + 1] = lrun;
      float* dst = cO + base * 65;
#pragma unroll
      for (int d0 = 0; d0 < 4; ++d0)
#pragma unroll
        for (int r = 0; r < 16; ++r) dst[d0 * 16 + r] = oacc[d0][r];
    }
    __syncthreads();
    if (!Hf) {
      int base = wg * 64 + lane;
      float m2 = cML[base * 2], l2 = cML[base * 2 + 1];
      const float* src = cO + base * 65;
      float m  = fmaxf(mrun, m2);
      float e1 = fast_exp2(mrun - m), e2 = fast_exp2(m2 - m);
      float l  = lrun * e1 + l2 * e2;
      float inv = 1.0f / l;
      float f1 = e1 * inv, f2 = e2 * inv;
      float f1b[16], f2b[16];
#pragma unroll
      for (int r = 0; r < 16; ++r) {
        int ro = (r & 3) + 8 * (r >> 2) + 4 * hh;
        f1b[r] = __shfl(f1, ro, 64);
        f2b[r] = __shfl(f2, ro, 64);
      }
#pragma unroll
      for (int r = 0; r < 16; ++r) {
        int q = qrow_w + (r & 3) + 8 * (r >> 2) + 4 * hh;
#pragma unroll
        for (int d0 = 0; d0 < 4; ++d0) {
          int d = d0 * 32 + l31;
          float val = oacc[d0][r] * f1b[r] + src[d0 * 16 + r] * f2b[r];
          O[(size_t)(b * S_ + q) * DIM_ + h * HD + d] = f2bf(val);
        }
      }
    }
    __syncthreads();
  }
}

// ---------------- host launcher ----------------
extern "C" void kernel_launch(void* const* d_in, const int* in_sizes, int n_in,
                              void* d_out, int out_size, void* d_ws, size_t ws_size,
                              hipStream_t stream) {
  const float* x  = (const float*)d_in[0];
  const float* wq = (const float*)d_in[1];
  const float* wk = (const float*)d_in[2];
  const float* wv = (const float*)d_in[3];
  const float* wo = (const float*)d_in[4];
  const float* fc = (const float*)d_in[5];
  const float* fs = (const float*)d_in[6];
  float* out = (float*)d_out;

  char* ws = (char*)d_ws;
  size_t off = 0;
  auto alloc = [&](size_t bytes) -> ushort* {
    ushort* p = (ushort*)(ws + off);
    off += (bytes + 255) & ~(size_t)255;
    return p;
  };
  ushort* xb    = alloc((size_t)B_ * S_ * DIM_ * 2);        // 16MB
  ushort* wqkvb = alloc((size_t)QKVN * DIM_ * 2);           // 12.6MB
  ushort* wob   = alloc((size_t)DIM_ * DIM_ * 2);           // 8MB
  ushort* qkvr  = alloc((size_t)B_ * S_ * QKVN * 2);        // 25.2MB
  ushort* qr    = alloc((size_t)B_ * S_ * DIM_ * 2);        // 16MB
  ushort* kr    = alloc((size_t)B_ * S_ * NKV * HD * 2);    // 4MB
  ushort* vtb   = alloc((size_t)B_ * S_ * NKV * HD * 2);    // 4MB
  ushort* obf   = alloc((size_t)B_ * S_ * DIM_ * 2);        // 16MB
  (void)ws_size; (void)n_in; (void)in_sizes; (void)out_size;

  // converts (weights concatenated into fused [3072][2048] buffer)
  cvt_kernel<<<(B_ * S_ * DIM_) / 1024, 256, 0, stream>>>(x,  xb, B_ * S_ * DIM_);
  cvt_kernel<<<(DIM_ * DIM_) / 1024,     256, 0, stream>>>(wq, wqkvb,                 DIM_ * DIM_);
  cvt_kernel<<<(NKV * HD * DIM_) / 1024, 256, 0, stream>>>(wk, wqkvb + 2048 * DIM_,   NKV * HD * DIM_);
  cvt_kernel<<<(NKV * HD * DIM_) / 1024, 256, 0, stream>>>(wv, wqkvb + 2560 * DIM_,   NKV * HD * DIM_);
  cvt_kernel<<<(DIM_ * DIM_) / 1024,     256, 0, stream>>>(wo, wob, DIM_ * DIM_);

  // fused QKV projection: [4096, 2048] x [3072, 2048]^T -> [4096, 3072]
  gemm256<ushort><<<(B_ * S_ / 256) * (QKVN / 256), 512, 0, stream>>>(xb, wqkvb, qkvr,
                                                                     B_ * S_, QKVN, DIM_);

  // rope + relayout; Q scale = 1/sqrt(128) * log2(e) (softmax runs in base 2)
  const float qscale = 0.08838834764831845f * 1.4426950408889634f;
  rope_kernel<<<(B_ * S_ * NH  * 16) / 256, 256, 0, stream>>>(qkvr,        fc, fs, qr, NH,  QKVN, qscale);
  rope_kernel<<<(B_ * S_ * NKV * 16) / 256, 256, 0, stream>>>(qkvr + 2048, fc, fs, kr, NKV, QKVN, 1.0f);
  vtrans_kernel<<<B_ * NKV * (S_ / 128), 256, 0, stream>>>(qkvr + 2560, vtb, QKVN);

  // attention: 256 blocks x 512 thr; uniform 17-tile chains per wave (k-split + pair)
  attn_kernel<<<B_ * NH * 8, 512, 0, stream>>>(qr, kr, vtb, obf);

  // output projection -> f32 d_out
  gemm256<float><<<(B_ * S_ / 256) * (DIM_ / 256), 512, 0, stream>>>(obf, wob, out, B_ * S_, DIM_, DIM_);
}

// Round 9
// 196.426 us; speedup vs baseline: 1.0715x; 1.0715x over previous
//
#include <hip/hip_runtime.h>
#include <hip/hip_bf16.h>

// Problem constants
#define B_   2
#define S_   2048
#define DIM_ 2048
#define NH   16
#define NKV  4
#define HD   128
#define QKVN 3072   // fused projection width: 2048 (Q) + 512 (K) + 512 (V)

typedef __attribute__((ext_vector_type(8)))  short  sv8;   // 8 x bf16 (MFMA operand)
typedef __attribute__((ext_vector_type(8)))  ushort usv8;
typedef __attribute__((ext_vector_type(4)))  float  fv4;
typedef __attribute__((ext_vector_type(16))) float  fv16;

__device__ __forceinline__ float fast_exp2(float x) {
  return __builtin_amdgcn_exp2f(x);   // v_exp_f32 (base-2)
}

__device__ __forceinline__ ushort f2bf(float f) {
  __hip_bfloat16 h = __float2bfloat16(f);
  union { __hip_bfloat16 h; ushort u; } c; c.h = h; return c.u;
}
__device__ __forceinline__ float bf2f(ushort u) {
  union { unsigned int i; float f; } c; c.i = ((unsigned)u) << 16; return c.f;
}

// pack two f32 -> two bf16 in one u32 (src0 -> low 16, src1 -> high 16)
__device__ __forceinline__ unsigned int cvtpk(float lo, float hi) {
  unsigned int r;
  asm("v_cvt_pk_bf16_f32 %0, %1, %2" : "=v"(r) : "v"(lo), "v"(hi));
  return r;
}
// exchange with partner lane (lane ^ 32)
__device__ __forceinline__ unsigned int xhalf(unsigned int x) {
  return (unsigned int)__shfl_xor((int)x, 32, 64);
}

// tree reductions over a 16-vector (depth 5, ILP-friendly)
__device__ __forceinline__ float tmax16(const fv16& v) {
  float a = fmaxf(fmaxf(v[0], v[1]),  fmaxf(v[2], v[3]));
  float b = fmaxf(fmaxf(v[4], v[5]),  fmaxf(v[6], v[7]));
  float c = fmaxf(fmaxf(v[8], v[9]),  fmaxf(v[10], v[11]));
  float d = fmaxf(fmaxf(v[12], v[13]), fmaxf(v[14], v[15]));
  return fmaxf(fmaxf(a, b), fmaxf(c, d));
}
__device__ __forceinline__ float tsum16(const fv16& v) {
  float a = (v[0] + v[1]) + (v[2] + v[3]);
  float b = (v[4] + v[5]) + (v[6] + v[7]);
  float c = (v[8] + v[9]) + (v[10] + v[11]);
  float d = (v[12] + v[13]) + (v[14] + v[15]);
  return (a + b) + (c + d);
}

// async global->LDS, 16B per lane; LDS dest is wave-uniform base (HW adds lane*16).
__device__ __forceinline__ void async16(const void* g, void* l) {
  __builtin_amdgcn_global_load_lds(
      (const __attribute__((address_space(1))) unsigned int*)g,
      (__attribute__((address_space(3))) unsigned int*)l, 16, 0, 0);
}

// ---------------- f32 -> bf16 convert ----------------
__global__ void cvt_kernel(const float* __restrict__ in, ushort* __restrict__ out, int n) {
  int i = (blockIdx.x * 256 + threadIdx.x) * 4;
  if (i >= n) return;
  fv4 v = *(const fv4*)(in + i);
  ushort4 o;
  o.x = f2bf(v[0]); o.y = f2bf(v[1]); o.z = f2bf(v[2]); o.w = f2bf(v[3]);
  *(ushort4*)(out + i) = o;
}

// ---------------- RoPE (+ scale), relayout to (B, heads, S, HD) ----------------
__global__ void rope_kernel(const ushort* __restrict__ raw, const float* __restrict__ fc,
                            const float* __restrict__ fs, ushort* __restrict__ out,
                            int heads, int rowstride, float scale) {
  int t = blockIdx.x * 256 + threadIdx.x;   // B*S*heads*16 threads, 8 elems each
  int grp = t & 15;
  int h   = (t >> 4) % heads;
  int s   = ((t >> 4) / heads) % S_;
  int b   = t / (16 * heads * S_);
  const ushort* src = raw + (size_t)(b * S_ + s) * rowstride + h * HD + grp * 8;
  sv8 v = *(const sv8*)src;
  fv4 c  = *(const fv4*)(fc + s * 64 + grp * 4);
  fv4 sn = *(const fv4*)(fs + s * 64 + grp * 4);
  sv8 o;
#pragma unroll
  for (int p = 0; p < 4; ++p) {
    float re = bf2f((ushort)v[2 * p]);
    float im = bf2f((ushort)v[2 * p + 1]);
    float orr = (re * c[p] - im * sn[p]) * scale;
    float oi  = (re * sn[p] + im * c[p]) * scale;
    o[2 * p]     = (short)f2bf(orr);
    o[2 * p + 1] = (short)f2bf(oi);
  }
  ushort* dst = out + ((size_t)(b * heads + h) * S_ + s) * HD + grp * 8;
  *(sv8*)dst = o;
}

// ---------------- V transpose: rows of fused qkv -> (B,KVH,HD,S) ----------------
__global__ __launch_bounds__(256) void vtrans_kernel(const ushort* __restrict__ vraw,
                                                     ushort* __restrict__ vt, int rowstride) {
  __shared__ ushort tile[128][136];
  int blk = blockIdx.x;            // (b*NKV+kv)*16 + st
  int st  = blk & 15;
  int kvb = blk >> 4;
  int kv  = kvb & 3;
  int b   = kvb >> 2;
  int s0  = st << 7;
#pragma unroll
  for (int it = 0; it < 8; ++it) {
    int t = it * 256 + threadIdx.x;
    int srow = t >> 4;
    int d8 = (t & 15) * 8;
    usv8 v = *(const usv8*)(vraw + (size_t)(b * S_ + s0 + srow) * rowstride + kv * HD + d8);
#pragma unroll
    for (int j = 0; j < 8; ++j) tile[d8 + j][srow] = v[j];
  }
  __syncthreads();
#pragma unroll
  for (int it = 0; it < 8; ++it) {
    int t = it * 256 + threadIdx.x;
    int d = t >> 4;
    int s8 = (t & 15) * 8;
    usv8 o;
#pragma unroll
    for (int j = 0; j < 8; ++j) o[j] = tile[d][s8 + j];
    *(usv8*)(vt + ((size_t)(b * NKV + kv) * HD + d) * S_ + s0 + s8) = o;
  }
}

// ---------------- GEMM: C[M,N] = A[M,K] * B[N,K]^T  (bf16 in, OutT out) ----------------
// 128x128 tile, BK=64, 4 waves (2x2 of 64x64), global_load_lds staging, XOR-swizzled LDS.
template <typename OutT>
__global__ __launch_bounds__(256) void gemm_bt(const ushort* __restrict__ A,
                                               const ushort* __restrict__ Bm,
                                               OutT* __restrict__ C,
                                               int M, int N, int K) {
  __shared__ ushort As[128 * 64];
  __shared__ ushort Bs[128 * 64];
  int nb = N >> 7;
  int bx = blockIdx.x % nb;
  int by = blockIdx.x / nb;
  int m0 = by << 7, n0 = bx << 7;
  int lane = threadIdx.x & 63, w = threadIdx.x >> 6;
  int l15 = lane & 15, lg = lane >> 4;
  int wm = (w >> 1) * 64, wn = (w & 1) * 64;

  const ushort* aSrc[4]; const ushort* bSrc[4];
  ushort* aDst[4]; ushort* bDst[4];
#pragma unroll
  for (int it = 0; it < 4; ++it) {
    int lin = it * 4096 + w * 1024 + lane * 16;   // byte offset into 16KB tile
    int row = lin >> 7;                           // 128B rows
    int cb  = (lin & 127) ^ ((row & 7) << 4);     // inverse swizzle on source col
    aSrc[it] = A  + (size_t)(m0 + row) * K + (cb >> 1);
    bSrc[it] = Bm + (size_t)(n0 + row) * K + (cb >> 1);
    aDst[it] = As + ((it * 4096 + w * 1024) >> 1);
    bDst[it] = Bs + ((it * 4096 + w * 1024) >> 1);
  }

  fv4 acc[4][4] = {};

  for (int kt = 0; kt < K; kt += 64) {
#pragma unroll
    for (int it = 0; it < 4; ++it) async16(aSrc[it] + kt, aDst[it]);
#pragma unroll
    for (int it = 0; it < 4; ++it) async16(bSrc[it] + kt, bDst[it]);
    __syncthreads();
#pragma unroll
    for (int kk = 0; kk < 2; ++kk) {
      sv8 af[4], bfr[4];
#pragma unroll
      for (int i = 0; i < 4; ++i) {
        int row = wm + i * 16 + l15;
        int byt = row * 128 + ((kk * 64 + (lg << 4)) ^ ((row & 7) << 4));
        af[i] = *(const sv8*)((const char*)As + byt);
      }
#pragma unroll
      for (int j = 0; j < 4; ++j) {
        int row = wn + j * 16 + l15;
        int byt = row * 128 + ((kk * 64 + (lg << 4)) ^ ((row & 7) << 4));
        bfr[j] = *(const sv8*)((const char*)Bs + byt);
      }
#pragma unroll
      for (int i = 0; i < 4; ++i)
#pragma unroll
        for (int j = 0; j < 4; ++j)
          acc[i][j] = __builtin_amdgcn_mfma_f32_16x16x32_bf16(af[i], bfr[j], acc[i][j], 0, 0, 0);
    }
    __syncthreads();
  }

#pragma unroll
  for (int i = 0; i < 4; ++i)
#pragma unroll
    for (int j = 0; j < 4; ++j)
#pragma unroll
      for (int r = 0; r < 4; ++r) {
        int row = m0 + wm + i * 16 + (lg << 2) + r;
        int col = n0 + wn + j * 16 + l15;
        if constexpr (sizeof(OutT) == 2) C[(size_t)row * N + col] = (OutT)f2bf(acc[i][j][r]);
        else                             C[(size_t)row * N + col] = (OutT)acc[i][j][r];
      }
}

// ---------------- 8-phase-class 256x128 GEMM (o-proj): grid fills 256 CUs ----------
// 512 thr = 8 waves (2M x 4N), per-wave 128x32 out. BK=64. LDS 96KB:
// [buf][A0, A1, B] 16KB parts ([128 rows][128B], (row&7)<<4 XOR swizzle).
// 4 phases/K-tile; staging of region strictly after its last reads (barrier-
// separated: B staged P3 after reads end P2; A staged P4 after reads end P3).
// Counted vmcnt(6) = 6 loads of tile T+2 in flight -> tile T+1 landed.
template <typename OutT>
__global__ __launch_bounds__(512) void gemmOP(const ushort* __restrict__ A,
                                              const ushort* __restrict__ Bm,
                                              OutT* __restrict__ C,
                                              int M, int N, int K) {
  __shared__ __align__(16) ushort SM[49152];   // 96KB
  int nb = N >> 7;
  int bx = blockIdx.x % nb, by = blockIdx.x / nb;
  int m0 = by << 8, n0 = bx << 7;
  int tid = threadIdx.x;
  int lane = tid & 63, w = tid >> 6;
  int l15 = lane & 15, lg = lane >> 4;
  int wm = (w >> 2) * 128;          // wave M offset (0/128)
  int wn = (w & 3) * 32;            // wave N offset
  int pA = (w >> 2);                // A part 0/1

  // staging sources (per-thread, pre-swizzled column)
  int srow = tid >> 3;
  int cb   = ((tid & 7) * 16) ^ ((srow & 7) << 4);
  const ushort* sA0 = A  + (size_t)(m0 + srow) * K + (cb >> 1);
  const ushort* sB0 = Bm + (size_t)(n0 + srow) * K + (cb >> 1);
  const ushort* srcs[3] = { sA0, sA0 + (size_t)128 * K, sB0 };
  size_t rstep = (size_t)64 * K;

  int nkt = K >> 6;

  auto STG = [&](int part, int t, int db) {
    ushort* d0 = SM + db * 24576 + part * 8192 + (w << 9);
    const ushort* s0 = srcs[part] + t * 64;
    async16(s0, d0);
    async16(s0 + rstep, d0 + 4096);
  };

  fv4 acc[8][2] = {};
  sv8 a[4][2], b[2], b2[2];

  // prologue: tiles 0 and 1 fully staged (6 loads each)
#pragma unroll
  for (int p = 0; p < 3; ++p) STG(p, 0, 0);
  {
    int t1 = 1 < nkt ? 1 : 0;
#pragma unroll
    for (int p = 0; p < 3; ++p) STG(p, t1, 1);
  }
  asm volatile("s_waitcnt vmcnt(6)");
  __builtin_amdgcn_s_barrier();

  for (int t = 0; t < nkt; ++t) {
    int db = t & 1;
    int t2 = t + 2 < nkt ? t + 2 : nkt - 1;
    const char* Ab = (const char*)SM + db * 49152 + pA * 16384;
    const char* Bb = (const char*)SM + db * 49152 + 32768;

    // ---- P1: ds_read A m0-3 (8), B j0 (2); MFMA m0-3 x j0 ----
#pragma unroll
    for (int m = 0; m < 4; ++m)
#pragma unroll
      for (int kk = 0; kk < 2; ++kk) {
        int row = m * 16 + l15;
        a[m][kk] = *(const sv8*)(Ab + row * 128 + ((kk * 64 + lg * 16) ^ ((row & 7) << 4)));
      }
#pragma unroll
    for (int kk = 0; kk < 2; ++kk) {
      int row = wn + l15;
      b[kk] = *(const sv8*)(Bb + row * 128 + ((kk * 64 + lg * 16) ^ ((row & 7) << 4)));
    }
    __builtin_amdgcn_s_barrier();
    asm volatile("s_waitcnt lgkmcnt(0)");
    __builtin_amdgcn_s_setprio(1);
#pragma unroll
    for (int m = 0; m < 4; ++m)
#pragma unroll
      for (int kk = 0; kk < 2; ++kk)
        acc[m][0] = __builtin_amdgcn_mfma_f32_16x16x32_bf16(a[m][kk], b[kk], acc[m][0], 0, 0, 0);
    __builtin_amdgcn_s_setprio(0);
    __builtin_amdgcn_s_barrier();

    // ---- P2: ds_read B j1 (2); MFMA m0-3 x j1 ----
#pragma unroll
    for (int kk = 0; kk < 2; ++kk) {
      int row = wn + 16 + l15;
      b2[kk] = *(const sv8*)(Bb + row * 128 + ((kk * 64 + lg * 16) ^ ((row & 7) << 4)));
    }
    __builtin_amdgcn_s_barrier();
    asm volatile("s_waitcnt lgkmcnt(0)");
    __builtin_amdgcn_s_setprio(1);
#pragma unroll
    for (int m = 0; m < 4; ++m)
#pragma unroll
      for (int kk = 0; kk < 2; ++kk)
        acc[m][1] = __builtin_amdgcn_mfma_f32_16x16x32_bf16(a[m][kk], b2[kk], acc[m][1], 0, 0, 0);
    __builtin_amdgcn_s_setprio(0);
    __builtin_amdgcn_s_barrier();

    // ---- P3: ds_read A m4-7 (8); stage (T+2)B; MFMA m4-7 x j1 ----
#pragma unroll
    for (int m = 0; m < 4; ++m)
#pragma unroll
      for (int kk = 0; kk < 2; ++kk) {
        int row = 64 + m * 16 + l15;
        a[m][kk] = *(const sv8*)(Ab + row * 128 + ((kk * 64 + lg * 16) ^ ((row & 7) << 4)));
      }
    STG(2, t2, db);
    __builtin_amdgcn_s_barrier();
    asm volatile("s_waitcnt lgkmcnt(0)");
    __builtin_amdgcn_s_setprio(1);
#pragma unroll
    for (int m = 0; m < 4; ++m)
#pragma unroll
      for (int kk = 0; kk < 2; ++kk)
        acc[m + 4][1] = __builtin_amdgcn_mfma_f32_16x16x32_bf16(a[m][kk], b2[kk], acc[m + 4][1], 0, 0, 0);
    __builtin_amdgcn_s_setprio(0);
    __builtin_amdgcn_s_barrier();

    // ---- P4: stage (T+2)A0,A1; vmcnt(6) -> tile T+1 landed; MFMA m4-7 x j0 ----
    STG(0, t2, db);
    STG(1, t2, db);
    asm volatile("s_waitcnt vmcnt(6)");
    __builtin_amdgcn_s_barrier();
    __builtin_amdgcn_s_setprio(1);
#pragma unroll
    for (int m = 0; m < 4; ++m)
#pragma unroll
      for (int kk = 0; kk < 2; ++kk)
        acc[m + 4][0] = __builtin_amdgcn_mfma_f32_16x16x32_bf16(a[m][kk], b[kk], acc[m + 4][0], 0, 0, 0);
    __builtin_amdgcn_s_setprio(0);
    __builtin_amdgcn_s_barrier();
  }

  asm volatile("s_waitcnt vmcnt(0)");
#pragma unroll
  for (int m = 0; m < 8; ++m)
#pragma unroll
    for (int j = 0; j < 2; ++j)
#pragma unroll
      for (int r = 0; r < 4; ++r) {
        int row = m0 + wm + m * 16 + lg * 4 + r;
        int col = n0 + wn + j * 16 + l15;
        if constexpr (sizeof(OutT) == 2) C[(size_t)row * N + col] = (OutT)f2bf(acc[m][j][r]);
        else                             C[(size_t)row * N + col] = (OutT)acc[m][j][r];
      }
}

// ---------------- Flash attention (causal, GQA) ---------------- (unchanged from r7)
__global__ __launch_bounds__(512, 2) void attn_kernel(const ushort* __restrict__ Q,
                                                      const ushort* __restrict__ Kr,
                                                      const ushort* __restrict__ Vt,
                                                      ushort* __restrict__ O) {
  __shared__ __align__(16) ushort SMEM[65536];   // 128KB

  int blk = blockIdx.x;
  int bh  = blk & 31;
  int pr  = blk >> 5;
  int h   = bh & 15;
  int b   = bh >> 4;
  int kv  = h >> 2;
  int lane = threadIdx.x & 63, w = threadIdx.x >> 6;
  int wg = w & 3, Hf = w >> 2;
  int l31 = lane & 31, hh = lane >> 5;

  const ushort* Qbase = Q  + (size_t)(b * NH  + h ) * S_ * HD;
  const ushort* Kbase = Kr + (size_t)(b * NKV + kv) * S_ * HD;
  const ushort* Vbase = Vt + (size_t)(b * NKV + kv) * HD * S_;

  const ushort* kSrc[4]; ushort* kDst[2][4];
  const ushort* vSrc[4]; ushort* vDst[2][4];
#pragma unroll
  for (int it = 0; it < 4; ++it) {
    int lin = it * 4096 + wg * 1024 + lane * 16;
    { int row = lin >> 8; int cbv = (lin & 255) ^ ((row & 7) << 4);
      kSrc[it] = Kbase + (size_t)row * HD + (cbv >> 1); }
    { int row = lin >> 7; int cbv = (lin & 127) ^ ((row & 7) << 4);
      vSrc[it] = Vbase + (size_t)row * S_ + (cbv >> 1); }
#pragma unroll
    for (int buf = 0; buf < 2; ++buf) {
      kDst[buf][it] = SMEM + Hf * 16384 + buf * 8192 + ((it * 4096 + wg * 1024) >> 1);
      vDst[buf][it] = SMEM + 32768 + Hf * 16384 + buf * 8192 + ((it * 4096 + wg * 1024) >> 1);
    }
  }

  float* cML = (float*)SMEM;
  float* cO  = (float*)SMEM + 512;

  for (int pass = 0; pass < 2; ++pass) {
    int qt = pass ? (15 - pr) : pr;
    int q0 = qt << 7;
    int qrow_w = q0 + wg * 32;
    int myq    = qrow_w + l31;
    int nj     = qt + 1;
    int ktbase = Hf * nj;

    sv8 qf[8];
#pragma unroll
    for (int kk = 0; kk < 8; ++kk)
      qf[kk] = *(const sv8*)(Qbase + (size_t)myq * HD + kk * 16 + hh * 8);

    fv16 oacc[4] = {};
    float mrun = -1e30f, lrun = 0.f;

    {
      size_t k0 = (size_t)ktbase << 6;
#pragma unroll
      for (int it = 0; it < 4; ++it) async16(kSrc[it] + k0 * HD, kDst[0][it]);
#pragma unroll
      for (int it = 0; it < 4; ++it) async16(vSrc[it] + k0,      vDst[0][it]);
    }

    for (int j = 0; j < nj; ++j) {
      int cur = j & 1, nxt = cur ^ 1;
      __syncthreads();
      if (j + 1 < nj) {
        size_t k0n = (size_t)(ktbase + j + 1) << 6;
#pragma unroll
        for (int it = 0; it < 4; ++it) async16(kSrc[it] + k0n * HD, kDst[nxt][it]);
#pragma unroll
        for (int it = 0; it < 4; ++it) async16(vSrc[it] + k0n,      vDst[nxt][it]);
      }
      const char* KsC = (const char*)(SMEM + Hf * 16384 + cur * 8192);
      const char* VsC = (const char*)(SMEM + 32768 + Hf * 16384 + cur * 8192);
      int k0 = (ktbase + j) << 6;

      fv16 sacc[2] = {};
      __builtin_amdgcn_s_setprio(1);
#pragma unroll
      for (int kk = 0; kk < 8; ++kk) {
        int cbq = kk * 32 + hh * 16;
        int r0 = l31, r1 = 32 + l31;
        sv8 kf0 = *(const sv8*)(KsC + r0 * 256 + (cbq ^ ((r0 & 7) << 4)));
        sv8 kf1 = *(const sv8*)(KsC + r1 * 256 + (cbq ^ ((r1 & 7) << 4)));
        sacc[0] = __builtin_amdgcn_mfma_f32_32x32x16_bf16(kf0, qf[kk], sacc[0], 0, 0, 0);
        sacc[1] = __builtin_amdgcn_mfma_f32_32x32x16_bf16(kf1, qf[kk], sacc[1], 0, 0, 0);
      }
      __builtin_amdgcn_s_setprio(0);

      if (k0 + 63 > qrow_w) {
        int thr = myq - k0 - 4 * hh;
#pragma unroll
        for (int t = 0; t < 2; ++t)
#pragma unroll
          for (int r = 0; r < 16; ++r) {
            int kp = t * 32 + (r & 3) + 8 * (r >> 2);
            if (kp > thr) sacc[t][r] = -1e38f;
          }
      }

      float tmax = fmaxf(tmax16(sacc[0]), tmax16(sacc[1]));
      tmax = fmaxf(tmax, __shfl_xor(tmax, 32, 64));

      if (__any(tmax > mrun + 8.0f)) {
        float mnew = fmaxf(mrun, tmax);
        float esc  = fast_exp2(mrun - mnew);
        lrun *= esc;
        float er[16];
#pragma unroll
        for (int r = 0; r < 16; ++r) er[r] = __shfl(esc, (r & 3) + 8 * (r >> 2) + 4 * hh, 64);
#pragma unroll
        for (int d0 = 0; d0 < 4; ++d0)
#pragma unroll
          for (int r = 0; r < 16; ++r) oacc[d0][r] *= er[r];
        mrun = mnew;
      }

#pragma unroll
      for (int t = 0; t < 2; ++t)
#pragma unroll
        for (int r = 0; r < 16; ++r) sacc[t][r] = fast_exp2(sacc[t][r] - mrun);
      float psum = tsum16(sacc[0]) + tsum16(sacc[1]);
      psum += __shfl_xor(psum, 32, 64);
      lrun += psum;

      union Frag { unsigned int u[4]; sv8 v; } pa[4];
#pragma unroll
      for (int t = 0; t < 2; ++t)
#pragma unroll
        for (int half = 0; half < 2; ++half) {
          int cbq = half * 8;
          unsigned int a0 = cvtpk(sacc[t][cbq + 0], sacc[t][cbq + 1]);
          unsigned int a1 = cvtpk(sacc[t][cbq + 2], sacc[t][cbq + 3]);
          unsigned int b0 = cvtpk(sacc[t][cbq + 4], sacc[t][cbq + 5]);
          unsigned int b1 = cvtpk(sacc[t][cbq + 6], sacc[t][cbq + 7]);
          unsigned int a0p = xhalf(a0), a1p = xhalf(a1);
          unsigned int b0p = xhalf(b0), b1p = xhalf(b1);
          pa[2 * t + half].u[0] = hh ? b0p : a0;
          pa[2 * t + half].u[1] = hh ? b1p : a1;
          pa[2 * t + half].u[2] = hh ? b0  : a0p;
          pa[2 * t + half].u[3] = hh ? b1  : a1p;
        }

      __builtin_amdgcn_s_setprio(1);
#pragma unroll
      for (int ks = 0; ks < 4; ++ks) {
        int cbq = ks * 32 + hh * 16;
#pragma unroll
        for (int d0 = 0; d0 < 4; ++d0) {
          int row = d0 * 32 + l31;
          sv8 vf = *(const sv8*)(VsC + row * 128 + (cbq ^ ((row & 7) << 4)));
          oacc[d0] = __builtin_amdgcn_mfma_f32_32x32x16_bf16(pa[ks].v, vf, oacc[d0], 0, 0, 0);
        }
      }
      __builtin_amdgcn_s_setprio(0);
    }

    __syncthreads();
    if (Hf) {
      int base = wg * 64 + lane;
      cML[base * 2]     = mrun;
      cML[base * 2 + 1] = lrun;
      float* dst = cO + base * 65;
#pragma unroll
      for (int d0 = 0; d0 < 4; ++d0)
#pragma unroll
        for (int r = 0; r < 16; ++r) dst[d0 * 16 + r] = oacc[d0][r];
    }
    __syncthreads();
    if (!Hf) {
      int base = wg * 64 + lane;
      float m2 = cML[base * 2], l2 = cML[base * 2 + 1];
      const float* src = cO + base * 65;
      float m  = fmaxf(mrun, m2);
      float e1 = fast_exp2(mrun - m), e2 = fast_exp2(m2 - m);
      float l  = lrun * e1 + l2 * e2;
      float inv = 1.0f / l;
      float f1 = e1 * inv, f2 = e2 * inv;
      float f1b[16], f2b[16];
#pragma unroll
      for (int r = 0; r < 16; ++r) {
        int ro = (r & 3) + 8 * (r >> 2) + 4 * hh;
        f1b[r] = __shfl(f1, ro, 64);
        f2b[r] = __shfl(f2, ro, 64);
      }
#pragma unroll
      for (int r = 0; r < 16; ++r) {
        int q = qrow_w + (r & 3) + 8 * (r >> 2) + 4 * hh;
#pragma unroll
        for (int d0 = 0; d0 < 4; ++d0) {
          int d = d0 * 32 + l31;
          float val = oacc[d0][r] * f1b[r] + src[d0 * 16 + r] * f2b[r];
          O[(size_t)(b * S_ + q) * DIM_ + h * HD + d] = f2bf(val);
        }
      }
    }
    __syncthreads();
  }
}

// ---------------- host launcher ----------------
extern "C" void kernel_launch(void* const* d_in, const int* in_sizes, int n_in,
                              void* d_out, int out_size, void* d_ws, size_t ws_size,
                              hipStream_t stream) {
  const float* x  = (const float*)d_in[0];
  const float* wq = (const float*)d_in[1];
  const float* wk = (const float*)d_in[2];
  const float* wv = (const float*)d_in[3];
  const float* wo = (const float*)d_in[4];
  const float* fc = (const float*)d_in[5];
  const float* fs = (const float*)d_in[6];
  float* out = (float*)d_out;

  char* ws = (char*)d_ws;
  size_t off = 0;
  auto alloc = [&](size_t bytes) -> ushort* {
    ushort* p = (ushort*)(ws + off);
    off += (bytes + 255) & ~(size_t)255;
    return p;
  };
  ushort* xb    = alloc((size_t)B_ * S_ * DIM_ * 2);        // 16MB
  ushort* wqkvb = alloc((size_t)QKVN * DIM_ * 2);           // 12.6MB
  ushort* wob   = alloc((size_t)DIM_ * DIM_ * 2);           // 8MB
  ushort* qkvr  = alloc((size_t)B_ * S_ * QKVN * 2);        // 25.2MB
  ushort* qr    = alloc((size_t)B_ * S_ * DIM_ * 2);        // 16MB
  ushort* kr    = alloc((size_t)B_ * S_ * NKV * HD * 2);    // 4MB
  ushort* vtb   = alloc((size_t)B_ * S_ * NKV * HD * 2);    // 4MB
  ushort* obf   = alloc((size_t)B_ * S_ * DIM_ * 2);        // 16MB
  (void)ws_size; (void)n_in; (void)in_sizes; (void)out_size;

  // converts (weights concatenated into fused [3072][2048] buffer)
  cvt_kernel<<<(B_ * S_ * DIM_) / 1024, 256, 0, stream>>>(x,  xb, B_ * S_ * DIM_);
  cvt_kernel<<<(DIM_ * DIM_) / 1024,     256, 0, stream>>>(wq, wqkvb,                 DIM_ * DIM_);
  cvt_kernel<<<(NKV * HD * DIM_) / 1024, 256, 0, stream>>>(wk, wqkvb + 2048 * DIM_,   NKV * HD * DIM_);
  cvt_kernel<<<(NKV * HD * DIM_) / 1024, 256, 0, stream>>>(wv, wqkvb + 2560 * DIM_,   NKV * HD * DIM_);
  cvt_kernel<<<(DIM_ * DIM_) / 1024,     256, 0, stream>>>(wo, wob, DIM_ * DIM_);

  // fused QKV projection: [4096, 2048] x [3072, 2048]^T -> [4096, 3072] (128^2 tiles, 768 blocks)
  gemm_bt<ushort><<<(B_ * S_ / 128) * (QKVN / 128), 256, 0, stream>>>(xb, wqkvb, qkvr,
                                                                     B_ * S_, QKVN, DIM_);

  // rope + relayout; Q scale = 1/sqrt(128) * log2(e) (softmax runs in base 2)
  const float qscale = 0.08838834764831845f * 1.4426950408889634f;
  rope_kernel<<<(B_ * S_ * NH  * 16) / 256, 256, 0, stream>>>(qkvr,        fc, fs, qr, NH,  QKVN, qscale);
  rope_kernel<<<(B_ * S_ * NKV * 16) / 256, 256, 0, stream>>>(qkvr + 2048, fc, fs, kr, NKV, QKVN, 1.0f);
  vtrans_kernel<<<B_ * NKV * (S_ / 128), 256, 0, stream>>>(qkvr + 2560, vtb, QKVN);

  // attention: 256 blocks x 512 thr; uniform 17-tile chains per wave (k-split + pair)
  attn_kernel<<<B_ * NH * 8, 512, 0, stream>>>(qr, kr, vtb, obf);

  // output projection -> f32 d_out (256x128 tiles, 16x16 = 256 blocks = 1/CU)
  gemmOP<float><<<(B_ * S_ / 256) * (DIM_ / 128), 512, 0, stream>>>(obf, wob, out, B_ * S_, DIM_, DIM_);
}

// Round 10
// 182.144 us; speedup vs baseline: 1.1556x; 1.0784x over previous
//
#include <hip/hip_runtime.h>
#include <hip/hip_bf16.h>

// Problem constants
#define B_   2
#define S_   2048
#define DIM_ 2048
#define NH   16
#define NKV  4
#define HD   128
#define QKVN 3072   // fused projection width: 2048 (Q) + 512 (K) + 512 (V)

typedef __attribute__((ext_vector_type(8)))  short  sv8;   // 8 x bf16 (MFMA operand)
typedef __attribute__((ext_vector_type(8)))  ushort usv8;
typedef __attribute__((ext_vector_type(4)))  float  fv4;
typedef __attribute__((ext_vector_type(16))) float  fv16;

__device__ __forceinline__ float fast_exp2(float x) {
  return __builtin_amdgcn_exp2f(x);   // v_exp_f32 (base-2)
}

__device__ __forceinline__ ushort f2bf(float f) {
  __hip_bfloat16 h = __float2bfloat16(f);
  union { __hip_bfloat16 h; ushort u; } c; c.h = h; return c.u;
}
__device__ __forceinline__ float bf2f(ushort u) {
  union { unsigned int i; float f; } c; c.i = ((unsigned)u) << 16; return c.f;
}

// pack two f32 -> two bf16 in one u32 (src0 -> low 16, src1 -> high 16)
__device__ __forceinline__ unsigned int cvtpk(float lo, float hi) {
  unsigned int r;
  asm("v_cvt_pk_bf16_f32 %0, %1, %2" : "=v"(r) : "v"(lo), "v"(hi));
  return r;
}
// exchange with partner lane (lane ^ 32)
__device__ __forceinline__ unsigned int xhalf(unsigned int x) {
  return (unsigned int)__shfl_xor((int)x, 32, 64);
}

// tree reductions over a 16-vector (depth 5, ILP-friendly)
__device__ __forceinline__ float tmax16(const fv16& v) {
  float a = fmaxf(fmaxf(v[0], v[1]),  fmaxf(v[2], v[3]));
  float b = fmaxf(fmaxf(v[4], v[5]),  fmaxf(v[6], v[7]));
  float c = fmaxf(fmaxf(v[8], v[9]),  fmaxf(v[10], v[11]));
  float d = fmaxf(fmaxf(v[12], v[13]), fmaxf(v[14], v[15]));
  return fmaxf(fmaxf(a, b), fmaxf(c, d));
}
__device__ __forceinline__ float tsum16(const fv16& v) {
  float a = (v[0] + v[1]) + (v[2] + v[3]);
  float b = (v[4] + v[5]) + (v[6] + v[7]);
  float c = (v[8] + v[9]) + (v[10] + v[11]);
  float d = (v[12] + v[13]) + (v[14] + v[15]);
  return (a + b) + (c + d);
}

// async global->LDS, 16B per lane; LDS dest is wave-uniform base (HW adds lane*16).
__device__ __forceinline__ void async16(const void* g, void* l) {
  __builtin_amdgcn_global_load_lds(
      (const __attribute__((address_space(1))) unsigned int*)g,
      (__attribute__((address_space(3))) unsigned int*)l, 16, 0, 0);
}

// ---------------- f32 -> bf16 convert (x) ----------------
__global__ void cvt_kernel(const float* __restrict__ in, ushort* __restrict__ out, int n) {
  int i = (blockIdx.x * 256 + threadIdx.x) * 4;
  if (i >= n) return;
  fv4 v = *(const fv4*)(in + i);
  ushort4 o;
  o.x = f2bf(v[0]); o.y = f2bf(v[1]); o.z = f2bf(v[2]); o.w = f2bf(v[3]);
  *(ushort4*)(out + i) = o;
}

// ---------------- fused weight convert: wq|wk|wv -> wqkvb, wo -> wob ----------------
__global__ void cvtw_kernel(const float* __restrict__ wq, const float* __restrict__ wk,
                            const float* __restrict__ wv, const float* __restrict__ wo,
                            ushort* __restrict__ wqkvb, ushort* __restrict__ wob) {
  const int NQ = 2048 * 2048, NK = 512 * 2048;
  int i = (blockIdx.x * 256 + threadIdx.x) * 4;   // ranges are 1024-aligned: no straddle
  const float* src; ushort* dst;
  if (i < NQ)               { src = wq + i;                 dst = wqkvb + i; }
  else if (i < NQ + NK)     { src = wk + (i - NQ);          dst = wqkvb + i; }
  else if (i < NQ + 2 * NK) { src = wv + (i - NQ - NK);     dst = wqkvb + i; }
  else                      { int j = i - (NQ + 2 * NK); src = wo + j; dst = wob + j; }
  fv4 v = *(const fv4*)src;
  ushort4 o;
  o.x = f2bf(v[0]); o.y = f2bf(v[1]); o.z = f2bf(v[2]); o.w = f2bf(v[3]);
  *(ushort4*)dst = o;
}

// ---------------- fused RoPE Q+K, relayout to (B, heads, S, HD) ----------------
__global__ void rope2_kernel(const ushort* __restrict__ qkv, const float* __restrict__ fc,
                             const float* __restrict__ fs, ushort* __restrict__ qr,
                             ushort* __restrict__ kr, float qscale) {
  int t = blockIdx.x * 256 + threadIdx.x;   // B*S*20*16 threads, 8 elems each
  int grp = t & 15;
  int u   = t >> 4;
  int h2  = u % 20;
  int s   = (u / 20) % S_;
  int b   = u / (20 * S_);
  bool isQ  = h2 < 16;
  int h     = isQ ? h2 : h2 - 16;
  int heads = isQ ? NH : NKV;
  float scale = isQ ? qscale : 1.0f;
  const ushort* src = qkv + (size_t)(b * S_ + s) * QKVN + (isQ ? 0 : 2048) + h * HD + grp * 8;
  sv8 v = *(const sv8*)src;
  fv4 c  = *(const fv4*)(fc + s * 64 + grp * 4);
  fv4 sn = *(const fv4*)(fs + s * 64 + grp * 4);
  sv8 o;
#pragma unroll
  for (int p = 0; p < 4; ++p) {
    float re = bf2f((ushort)v[2 * p]);
    float im = bf2f((ushort)v[2 * p + 1]);
    float orr = (re * c[p] - im * sn[p]) * scale;
    float oi  = (re * sn[p] + im * c[p]) * scale;
    o[2 * p]     = (short)f2bf(orr);
    o[2 * p + 1] = (short)f2bf(oi);
  }
  ushort* dst = (isQ ? qr : kr) + ((size_t)(b * heads + h) * S_ + s) * HD + grp * 8;
  *(sv8*)dst = o;
}

// ---------------- V transpose: rows of fused qkv -> (B,KVH,HD,S) ----------------
__global__ __launch_bounds__(256) void vtrans_kernel(const ushort* __restrict__ vraw,
                                                     ushort* __restrict__ vt, int rowstride) {
  __shared__ ushort tile[128][136];
  int blk = blockIdx.x;            // (b*NKV+kv)*16 + st
  int st  = blk & 15;
  int kvb = blk >> 4;
  int kv  = kvb & 3;
  int b   = kvb >> 2;
  int s0  = st << 7;
#pragma unroll
  for (int it = 0; it < 8; ++it) {
    int t = it * 256 + threadIdx.x;
    int srow = t >> 4;
    int d8 = (t & 15) * 8;
    usv8 v = *(const usv8*)(vraw + (size_t)(b * S_ + s0 + srow) * rowstride + kv * HD + d8);
#pragma unroll
    for (int j = 0; j < 8; ++j) tile[d8 + j][srow] = v[j];
  }
  __syncthreads();
#pragma unroll
  for (int it = 0; it < 8; ++it) {
    int t = it * 256 + threadIdx.x;
    int d = t >> 4;
    int s8 = (t & 15) * 8;
    usv8 o;
#pragma unroll
    for (int j = 0; j < 8; ++j) o[j] = tile[d][s8 + j];
    *(usv8*)(vt + ((size_t)(b * NKV + kv) * HD + d) * S_ + s0 + s8) = o;
  }
}

// ---------------- 4-phase 256x192 GEMM (QKV): 256 blocks = 1/CU ----------------
// 512 thr = 8 waves (2M x 4N), per-wave 128x48 out. BK=64. LDS 112KB:
// [buf][A0 16K][A1 16K][B 24K] ([row][128B], (row&7)<<4 XOR swizzle).
// Reads: P1 A-lo + B j0,j1; P2 A-hi + B j2 (A,B fully read by P2's end).
// Stages: P3 A(T+2) (4 loads), P4 B(T+2) (3 loads) + vmcnt(7) -> T+1 landed.
template <typename OutT>
__global__ __launch_bounds__(512) void gemm192(const ushort* __restrict__ A,
                                               const ushort* __restrict__ Bm,
                                               OutT* __restrict__ C,
                                               int M, int N, int K) {
  __shared__ __align__(16) ushort SM[57344];   // 112KB
  int nb = N / 192;
  int bx = blockIdx.x % nb, by = blockIdx.x / nb;
  int m0 = by << 8;
  int n0 = bx * 192;
  int tid = threadIdx.x;
  int lane = tid & 63, w = tid >> 6;
  int l15 = lane & 15, lg = lane >> 4;
  int wm = (w >> 2) * 128;          // wave M offset (0/128)
  int wn = (w & 3) * 48;            // wave N offset
  int pA = w >> 2;                  // A part 0/1

  // staging sources (per-thread, pre-swizzled column); one round = 512thr x 16B = 64 rows
  int srow = tid >> 3;
  int cb   = ((tid & 7) * 16) ^ ((srow & 7) << 4);
  const ushort* sA = A  + (size_t)(m0 + srow) * K + (cb >> 1);
  const ushort* sB = Bm + (size_t)(n0 + srow) * K + (cb >> 1);
  size_t rstep = (size_t)64 * K;
  int nkt = K >> 6;

  auto STG_A = [&](int t, int db) {   // 4 loads: rows 0..255 of A tile
    ushort* base = SM + db * 28672 + (w << 9);
    const ushort* a0 = sA + (size_t)t * 64;
    async16(a0,             base);
    async16(a0 + rstep,     base + 4096);
    async16(a0 + 2 * rstep, base + 8192);
    async16(a0 + 3 * rstep, base + 12288);
  };
  auto STG_B = [&](int t, int db) {   // 3 loads: rows 0..191 of B tile
    ushort* base = SM + db * 28672 + 16384 + (w << 9);
    const ushort* b0 = sB + (size_t)t * 64;
    async16(b0,             base);
    async16(b0 + rstep,     base + 4096);
    async16(b0 + 2 * rstep, base + 8192);
  };

  fv4 acc[8][3] = {};
  sv8 alo[4][2], ahi[4][2], b01[2][2], b2v[2];

  // prologue: tiles 0 and 1 fully staged (7 loads each)
  STG_A(0, 0); STG_B(0, 0);
  { int t1 = nkt > 1 ? 1 : 0; STG_A(t1, 1); STG_B(t1, 1); }
  asm volatile("s_waitcnt vmcnt(7)");
  __builtin_amdgcn_s_barrier();

  for (int t = 0; t < nkt; ++t) {
    int db = t & 1;
    int t2 = t + 2 < nkt ? t + 2 : nkt - 1;
    const char* Ab = (const char*)(SM + db * 28672) + pA * 16384;
    const char* Bb = (const char*)(SM + db * 28672) + 32768;

    // ---- P1: read A-lo(8) + B j0,j1(4); MFMA A-lo x {j0,j1} (16) ----
#pragma unroll
    for (int m = 0; m < 4; ++m)
#pragma unroll
      for (int kk = 0; kk < 2; ++kk) {
        int row = m * 16 + l15;
        alo[m][kk] = *(const sv8*)(Ab + row * 128 + ((kk * 64 + lg * 16) ^ ((row & 7) << 4)));
      }
#pragma unroll
    for (int j = 0; j < 2; ++j)
#pragma unroll
      for (int kk = 0; kk < 2; ++kk) {
        int row = wn + j * 16 + l15;
        b01[j][kk] = *(const sv8*)(Bb + row * 128 + ((kk * 64 + lg * 16) ^ ((row & 7) << 4)));
      }
    __builtin_amdgcn_s_barrier();
    asm volatile("s_waitcnt lgkmcnt(0)");
    __builtin_amdgcn_s_setprio(1);
#pragma unroll
    for (int m = 0; m < 4; ++m)
#pragma unroll
      for (int j = 0; j < 2; ++j)
#pragma unroll
        for (int kk = 0; kk < 2; ++kk)
          acc[m][j] = __builtin_amdgcn_mfma_f32_16x16x32_bf16(alo[m][kk], b01[j][kk], acc[m][j], 0, 0, 0);
    __builtin_amdgcn_s_setprio(0);
    __builtin_amdgcn_s_barrier();

    // ---- P2: read A-hi(8) + B j2(2); MFMA A-lo x j2 (8) ----
#pragma unroll
    for (int m = 0; m < 4; ++m)
#pragma unroll
      for (int kk = 0; kk < 2; ++kk) {
        int row = 64 + m * 16 + l15;
        ahi[m][kk] = *(const sv8*)(Ab + row * 128 + ((kk * 64 + lg * 16) ^ ((row & 7) << 4)));
      }
#pragma unroll
    for (int kk = 0; kk < 2; ++kk) {
      int row = wn + 32 + l15;
      b2v[kk] = *(const sv8*)(Bb + row * 128 + ((kk * 64 + lg * 16) ^ ((row & 7) << 4)));
    }
    __builtin_amdgcn_s_barrier();
    asm volatile("s_waitcnt lgkmcnt(0)");
    __builtin_amdgcn_s_setprio(1);
#pragma unroll
    for (int m = 0; m < 4; ++m)
#pragma unroll
      for (int kk = 0; kk < 2; ++kk)
        acc[m][2] = __builtin_amdgcn_mfma_f32_16x16x32_bf16(alo[m][kk], b2v[kk], acc[m][2], 0, 0, 0);
    __builtin_amdgcn_s_setprio(0);
    __builtin_amdgcn_s_barrier();

    // ---- P3: stage A(T+2); MFMA A-hi x {j0,j1} (16) ----
    STG_A(t2, db);
    __builtin_amdgcn_s_barrier();
    __builtin_amdgcn_s_setprio(1);
#pragma unroll
    for (int m = 0; m < 4; ++m)
#pragma unroll
      for (int j = 0; j < 2; ++j)
#pragma unroll
        for (int kk = 0; kk < 2; ++kk)
          acc[m + 4][j] = __builtin_amdgcn_mfma_f32_16x16x32_bf16(ahi[m][kk], b01[j][kk], acc[m + 4][j], 0, 0, 0);
    __builtin_amdgcn_s_setprio(0);
    __builtin_amdgcn_s_barrier();

    // ---- P4: stage B(T+2); vmcnt(7) -> T+1 landed; MFMA A-hi x j2 (8) ----
    STG_B(t2, db);
    asm volatile("s_waitcnt vmcnt(7)");
    __builtin_amdgcn_s_barrier();
    __builtin_amdgcn_s_setprio(1);
#pragma unroll
    for (int m = 0; m < 4; ++m)
#pragma unroll
      for (int kk = 0; kk < 2; ++kk)
        acc[m + 4][2] = __builtin_amdgcn_mfma_f32_16x16x32_bf16(ahi[m][kk], b2v[kk], acc[m + 4][2], 0, 0, 0);
    __builtin_amdgcn_s_setprio(0);
    __builtin_amdgcn_s_barrier();
  }

  asm volatile("s_waitcnt vmcnt(0)");
#pragma unroll
  for (int m = 0; m < 8; ++m)
#pragma unroll
    for (int j = 0; j < 3; ++j)
#pragma unroll
      for (int r = 0; r < 4; ++r) {
        int row = m0 + wm + m * 16 + lg * 4 + r;
        int col = n0 + wn + j * 16 + l15;
        if constexpr (sizeof(OutT) == 2) C[(size_t)row * N + col] = (OutT)f2bf(acc[m][j][r]);
        else                             C[(size_t)row * N + col] = (OutT)acc[m][j][r];
      }
}

// ---------------- 4-phase 256x128 GEMM (o-proj): 256 blocks = 1/CU ---------------
template <typename OutT>
__global__ __launch_bounds__(512) void gemmOP(const ushort* __restrict__ A,
                                              const ushort* __restrict__ Bm,
                                              OutT* __restrict__ C,
                                              int M, int N, int K) {
  __shared__ __align__(16) ushort SM[49152];   // 96KB
  int nb = N >> 7;
  int bx = blockIdx.x % nb, by = blockIdx.x / nb;
  int m0 = by << 8, n0 = bx << 7;
  int tid = threadIdx.x;
  int lane = tid & 63, w = tid >> 6;
  int l15 = lane & 15, lg = lane >> 4;
  int wm = (w >> 2) * 128;
  int wn = (w & 3) * 32;
  int pA = (w >> 2);

  int srow = tid >> 3;
  int cb   = ((tid & 7) * 16) ^ ((srow & 7) << 4);
  const ushort* sA0 = A  + (size_t)(m0 + srow) * K + (cb >> 1);
  const ushort* sB0 = Bm + (size_t)(n0 + srow) * K + (cb >> 1);
  const ushort* srcs[3] = { sA0, sA0 + (size_t)128 * K, sB0 };
  size_t rstep = (size_t)64 * K;

  int nkt = K >> 6;

  auto STG = [&](int part, int t, int db) {
    ushort* d0 = SM + db * 24576 + part * 8192 + (w << 9);
    const ushort* s0 = srcs[part] + t * 64;
    async16(s0, d0);
    async16(s0 + rstep, d0 + 4096);
  };

  fv4 acc[8][2] = {};
  sv8 a[4][2], b[2], b2[2];

#pragma unroll
  for (int p = 0; p < 3; ++p) STG(p, 0, 0);
  {
    int t1 = 1 < nkt ? 1 : 0;
#pragma unroll
    for (int p = 0; p < 3; ++p) STG(p, t1, 1);
  }
  asm volatile("s_waitcnt vmcnt(6)");
  __builtin_amdgcn_s_barrier();

  for (int t = 0; t < nkt; ++t) {
    int db = t & 1;
    int t2 = t + 2 < nkt ? t + 2 : nkt - 1;
    const char* Ab = (const char*)SM + db * 49152 + pA * 16384;
    const char* Bb = (const char*)SM + db * 49152 + 32768;

    // ---- P1: ds_read A m0-3 (8), B j0 (2); MFMA m0-3 x j0 ----
#pragma unroll
    for (int m = 0; m < 4; ++m)
#pragma unroll
      for (int kk = 0; kk < 2; ++kk) {
        int row = m * 16 + l15;
        a[m][kk] = *(const sv8*)(Ab + row * 128 + ((kk * 64 + lg * 16) ^ ((row & 7) << 4)));
      }
#pragma unroll
    for (int kk = 0; kk < 2; ++kk) {
      int row = wn + l15;
      b[kk] = *(const sv8*)(Bb + row * 128 + ((kk * 64 + lg * 16) ^ ((row & 7) << 4)));
    }
    __builtin_amdgcn_s_barrier();
    asm volatile("s_waitcnt lgkmcnt(0)");
    __builtin_amdgcn_s_setprio(1);
#pragma unroll
    for (int m = 0; m < 4; ++m)
#pragma unroll
      for (int kk = 0; kk < 2; ++kk)
        acc[m][0] = __builtin_amdgcn_mfma_f32_16x16x32_bf16(a[m][kk], b[kk], acc[m][0], 0, 0, 0);
    __builtin_amdgcn_s_setprio(0);
    __builtin_amdgcn_s_barrier();

    // ---- P2: ds_read B j1 (2); MFMA m0-3 x j1 ----
#pragma unroll
    for (int kk = 0; kk < 2; ++kk) {
      int row = wn + 16 + l15;
      b2[kk] = *(const sv8*)(Bb + row * 128 + ((kk * 64 + lg * 16) ^ ((row & 7) << 4)));
    }
    __builtin_amdgcn_s_barrier();
    asm volatile("s_waitcnt lgkmcnt(0)");
    __builtin_amdgcn_s_setprio(1);
#pragma unroll
    for (int m = 0; m < 4; ++m)
#pragma unroll
      for (int kk = 0; kk < 2; ++kk)
        acc[m][1] = __builtin_amdgcn_mfma_f32_16x16x32_bf16(a[m][kk], b2[kk], acc[m][1], 0, 0, 0);
    __builtin_amdgcn_s_setprio(0);
    __builtin_amdgcn_s_barrier();

    // ---- P3: ds_read A m4-7 (8); stage (T+2)B; MFMA m4-7 x j1 ----
#pragma unroll
    for (int m = 0; m < 4; ++m)
#pragma unroll
      for (int kk = 0; kk < 2; ++kk) {
        int row = 64 + m * 16 + l15;
        a[m][kk] = *(const sv8*)(Ab + row * 128 + ((kk * 64 + lg * 16) ^ ((row & 7) << 4)));
      }
    STG(2, t2, db);
    __builtin_amdgcn_s_barrier();
    asm volatile("s_waitcnt lgkmcnt(0)");
    __builtin_amdgcn_s_setprio(1);
#pragma unroll
    for (int m = 0; m < 4; ++m)
#pragma unroll
      for (int kk = 0; kk < 2; ++kk)
        acc[m + 4][1] = __builtin_amdgcn_mfma_f32_16x16x32_bf16(a[m][kk], b2[kk], acc[m + 4][1], 0, 0, 0);
    __builtin_amdgcn_s_setprio(0);
    __builtin_amdgcn_s_barrier();

    // ---- P4: stage (T+2)A0,A1; vmcnt(6) -> tile T+1 landed; MFMA m4-7 x j0 ----
    STG(0, t2, db);
    STG(1, t2, db);
    asm volatile("s_waitcnt vmcnt(6)");
    __builtin_amdgcn_s_barrier();
    __builtin_amdgcn_s_setprio(1);
#pragma unroll
    for (int m = 0; m < 4; ++m)
#pragma unroll
      for (int kk = 0; kk < 2; ++kk)
        acc[m + 4][0] = __builtin_amdgcn_mfma_f32_16x16x32_bf16(a[m][kk], b[kk], acc[m + 4][0], 0, 0, 0);
    __builtin_amdgcn_s_setprio(0);
    __builtin_amdgcn_s_barrier();
  }

  asm volatile("s_waitcnt vmcnt(0)");
#pragma unroll
  for (int m = 0; m < 8; ++m)
#pragma unroll
    for (int j = 0; j < 2; ++j)
#pragma unroll
      for (int r = 0; r < 4; ++r) {
        int row = m0 + wm + m * 16 + lg * 4 + r;
        int col = n0 + wn + j * 16 + l15;
        if constexpr (sizeof(OutT) == 2) C[(size_t)row * N + col] = (OutT)f2bf(acc[m][j][r]);
        else                             C[(size_t)row * N + col] = (OutT)acc[m][j][r];
      }
}

// ---------------- Flash attention (causal, GQA) ---------------- (unchanged)
__global__ __launch_bounds__(512, 2) void attn_kernel(const ushort* __restrict__ Q,
                                                      const ushort* __restrict__ Kr,
                                                      const ushort* __restrict__ Vt,
                                                      ushort* __restrict__ O) {
  __shared__ __align__(16) ushort SMEM[65536];   // 128KB

  int blk = blockIdx.x;
  int bh  = blk & 31;
  int pr  = blk >> 5;
  int h   = bh & 15;
  int b   = bh >> 4;
  int kv  = h >> 2;
  int lane = threadIdx.x & 63, w = threadIdx.x >> 6;
  int wg = w & 3, Hf = w >> 2;
  int l31 = lane & 31, hh = lane >> 5;

  const ushort* Qbase = Q  + (size_t)(b * NH  + h ) * S_ * HD;
  const ushort* Kbase = Kr + (size_t)(b * NKV + kv) * S_ * HD;
  const ushort* Vbase = Vt + (size_t)(b * NKV + kv) * HD * S_;

  const ushort* kSrc[4]; ushort* kDst[2][4];
  const ushort* vSrc[4]; ushort* vDst[2][4];
#pragma unroll
  for (int it = 0; it < 4; ++it) {
    int lin = it * 4096 + wg * 1024 + lane * 16;
    { int row = lin >> 8; int cbv = (lin & 255) ^ ((row & 7) << 4);
      kSrc[it] = Kbase + (size_t)row * HD + (cbv >> 1); }
    { int row = lin >> 7; int cbv = (lin & 127) ^ ((row & 7) << 4);
      vSrc[it] = Vbase + (size_t)row * S_ + (cbv >> 1); }
#pragma unroll
    for (int buf = 0; buf < 2; ++buf) {
      kDst[buf][it] = SMEM + Hf * 16384 + buf * 8192 + ((it * 4096 + wg * 1024) >> 1);
      vDst[buf][it] = SMEM + 32768 + Hf * 16384 + buf * 8192 + ((it * 4096 + wg * 1024) >> 1);
    }
  }

  float* cML = (float*)SMEM;
  float* cO  = (float*)SMEM + 512;

  for (int pass = 0; pass < 2; ++pass) {
    int qt = pass ? (15 - pr) : pr;
    int q0 = qt << 7;
    int qrow_w = q0 + wg * 32;
    int myq    = qrow_w + l31;
    int nj     = qt + 1;
    int ktbase = Hf * nj;

    sv8 qf[8];
#pragma unroll
    for (int kk = 0; kk < 8; ++kk)
      qf[kk] = *(const sv8*)(Qbase + (size_t)myq * HD + kk * 16 + hh * 8);

    fv16 oacc[4] = {};
    float mrun = -1e30f, lrun = 0.f;

    {
      size_t k0 = (size_t)ktbase << 6;
#pragma unroll
      for (int it = 0; it < 4; ++it) async16(kSrc[it] + k0 * HD, kDst[0][it]);
#pragma unroll
      for (int it = 0; it < 4; ++it) async16(vSrc[it] + k0,      vDst[0][it]);
    }

    for (int j = 0; j < nj; ++j) {
      int cur = j & 1, nxt = cur ^ 1;
      __syncthreads();
      if (j + 1 < nj) {
        size_t k0n = (size_t)(ktbase + j + 1) << 6;
#pragma unroll
        for (int it = 0; it < 4; ++it) async16(kSrc[it] + k0n * HD, kDst[nxt][it]);
#pragma unroll
        for (int it = 0; it < 4; ++it) async16(vSrc[it] + k0n,      vDst[nxt][it]);
      }
      const char* KsC = (const char*)(SMEM + Hf * 16384 + cur * 8192);
      const char* VsC = (const char*)(SMEM + 32768 + Hf * 16384 + cur * 8192);
      int k0 = (ktbase + j) << 6;

      fv16 sacc[2] = {};
      __builtin_amdgcn_s_setprio(1);
#pragma unroll
      for (int kk = 0; kk < 8; ++kk) {
        int cbq = kk * 32 + hh * 16;
        int r0 = l31, r1 = 32 + l31;
        sv8 kf0 = *(const sv8*)(KsC + r0 * 256 + (cbq ^ ((r0 & 7) << 4)));
        sv8 kf1 = *(const sv8*)(KsC + r1 * 256 + (cbq ^ ((r1 & 7) << 4)));
        sacc[0] = __builtin_amdgcn_mfma_f32_32x32x16_bf16(kf0, qf[kk], sacc[0], 0, 0, 0);
        sacc[1] = __builtin_amdgcn_mfma_f32_32x32x16_bf16(kf1, qf[kk], sacc[1], 0, 0, 0);
      }
      __builtin_amdgcn_s_setprio(0);

      if (k0 + 63 > qrow_w) {
        int thr = myq - k0 - 4 * hh;
#pragma unroll
        for (int t = 0; t < 2; ++t)
#pragma unroll
          for (int r = 0; r < 16; ++r) {
            int kp = t * 32 + (r & 3) + 8 * (r >> 2);
            if (kp > thr) sacc[t][r] = -1e38f;
          }
      }

      float tmax = fmaxf(tmax16(sacc[0]), tmax16(sacc[1]));
      tmax = fmaxf(tmax, __shfl_xor(tmax, 32, 64));

      if (__any(tmax > mrun + 8.0f)) {
        float mnew = fmaxf(mrun, tmax);
        float esc  = fast_exp2(mrun - mnew);
        lrun *= esc;
        float er[16];
#pragma unroll
        for (int r = 0; r < 16; ++r) er[r] = __shfl(esc, (r & 3) + 8 * (r >> 2) + 4 * hh, 64);
#pragma unroll
        for (int d0 = 0; d0 < 4; ++d0)
#pragma unroll
          for (int r = 0; r < 16; ++r) oacc[d0][r] *= er[r];
        mrun = mnew;
      }

#pragma unroll
      for (int t = 0; t < 2; ++t)
#pragma unroll
        for (int r = 0; r < 16; ++r) sacc[t][r] = fast_exp2(sacc[t][r] - mrun);
      float psum = tsum16(sacc[0]) + tsum16(sacc[1]);
      psum += __shfl_xor(psum, 32, 64);
      lrun += psum;

      union Frag { unsigned int u[4]; sv8 v; } pa[4];
#pragma unroll
      for (int t = 0; t < 2; ++t)
#pragma unroll
        for (int half = 0; half < 2; ++half) {
          int cbq = half * 8;
          unsigned int a0 = cvtpk(sacc[t][cbq + 0], sacc[t][cbq + 1]);
          unsigned int a1 = cvtpk(sacc[t][cbq + 2], sacc[t][cbq + 3]);
          unsigned int b0 = cvtpk(sacc[t][cbq + 4], sacc[t][cbq + 5]);
          unsigned int b1 = cvtpk(sacc[t][cbq + 6], sacc[t][cbq + 7]);
          unsigned int a0p = xhalf(a0), a1p = xhalf(a1);
          unsigned int b0p = xhalf(b0), b1p = xhalf(b1);
          pa[2 * t + half].u[0] = hh ? b0p : a0;
          pa[2 * t + half].u[1] = hh ? b1p : a1;
          pa[2 * t + half].u[2] = hh ? b0  : a0p;
          pa[2 * t + half].u[3] = hh ? b1  : a1p;
        }

      __builtin_amdgcn_s_setprio(1);
#pragma unroll
      for (int ks = 0; ks < 4; ++ks) {
        int cbq = ks * 32 + hh * 16;
#pragma unroll
        for (int d0 = 0; d0 < 4; ++d0) {
          int row = d0 * 32 + l31;
          sv8 vf = *(const sv8*)(VsC + row * 128 + (cbq ^ ((row & 7) << 4)));
          oacc[d0] = __builtin_amdgcn_mfma_f32_32x32x16_bf16(pa[ks].v, vf, oacc[d0], 0, 0, 0);
        }
      }
      __builtin_amdgcn_s_setprio(0);
    }

    __syncthreads();
    if (Hf) {
      int base = wg * 64 + lane;
      cML[base * 2]     = mrun;
      cML[base * 2 + 1] = lrun;
      float* dst = cO + base * 65;
#pragma unroll
      for (int d0 = 0; d0 < 4; ++d0)
#pragma unroll
        for (int r = 0; r < 16; ++r) dst[d0 * 16 + r] = oacc[d0][r];
    }
    __syncthreads();
    if (!Hf) {
      int base = wg * 64 + lane;
      float m2 = cML[base * 2], l2 = cML[base * 2 + 1];
      const float* src = cO + base * 65;
      float m  = fmaxf(mrun, m2);
      float e1 = fast_exp2(mrun - m), e2 = fast_exp2(m2 - m);
      float l  = lrun * e1 + l2 * e2;
      float inv = 1.0f / l;
      float f1 = e1 * inv, f2 = e2 * inv;
      float f1b[16], f2b[16];
#pragma unroll
      for (int r = 0; r < 16; ++r) {
        int ro = (r & 3) + 8 * (r >> 2) + 4 * hh;
        f1b[r] = __shfl(f1, ro, 64);
        f2b[r] = __shfl(f2, ro, 64);
      }
#pragma unroll
      for (int r = 0; r < 16; ++r) {
        int q = qrow_w + (r & 3) + 8 * (r >> 2) + 4 * hh;
#pragma unroll
        for (int d0 = 0; d0 < 4; ++d0) {
          int d = d0 * 32 + l31;
          float val = oacc[d0][r] * f1b[r] + src[d0 * 16 + r] * f2b[r];
          O[(size_t)(b * S_ + q) * DIM_ + h * HD + d] = f2bf(val);
        }
      }
    }
    __syncthreads();
  }
}

// ---------------- host launcher ----------------
extern "C" void kernel_launch(void* const* d_in, const int* in_sizes, int n_in,
                              void* d_out, int out_size, void* d_ws, size_t ws_size,
                              hipStream_t stream) {
  const float* x  = (const float*)d_in[0];
  const float* wq = (const float*)d_in[1];
  const float* wk = (const float*)d_in[2];
  const float* wv = (const float*)d_in[3];
  const float* wo = (const float*)d_in[4];
  const float* fc = (const float*)d_in[5];
  const float* fs = (const float*)d_in[6];
  float* out = (float*)d_out;

  char* ws = (char*)d_ws;
  size_t off = 0;
  auto alloc = [&](size_t bytes) -> ushort* {
    ushort* p = (ushort*)(ws + off);
    off += (bytes + 255) & ~(size_t)255;
    return p;
  };
  ushort* xb    = alloc((size_t)B_ * S_ * DIM_ * 2);        // 16MB
  ushort* wqkvb = alloc((size_t)QKVN * DIM_ * 2);           // 12.6MB
  ushort* wob   = alloc((size_t)DIM_ * DIM_ * 2);           // 8MB
  ushort* qkvr  = alloc((size_t)B_ * S_ * QKVN * 2);        // 25.2MB
  ushort* qr    = alloc((size_t)B_ * S_ * DIM_ * 2);        // 16MB
  ushort* kr    = alloc((size_t)B_ * S_ * NKV * HD * 2);    // 4MB
  ushort* vtb   = alloc((size_t)B_ * S_ * NKV * HD * 2);    // 4MB
  ushort* obf   = alloc((size_t)B_ * S_ * DIM_ * 2);        // 16MB
  (void)ws_size; (void)n_in; (void)in_sizes; (void)out_size;

  // converts: x, then all weights in one launch
  cvt_kernel<<<(B_ * S_ * DIM_) / 1024, 256, 0, stream>>>(x, xb, B_ * S_ * DIM_);
  cvtw_kernel<<<(2 * DIM_ * DIM_ + 2 * NKV * HD * DIM_) / 1024, 256, 0, stream>>>(
      wq, wk, wv, wo, wqkvb, wob);

  // fused QKV projection: [4096, 2048] x [3072, 2048]^T -> [4096, 3072] (256x192, 256 blocks)
  gemm192<ushort><<<(B_ * S_ / 256) * (QKVN / 192), 512, 0, stream>>>(xb, wqkvb, qkvr,
                                                                     B_ * S_, QKVN, DIM_);

  // fused rope Q+K; Q scale = 1/sqrt(128) * log2(e) (softmax runs in base 2)
  const float qscale = 0.08838834764831845f * 1.4426950408889634f;
  rope2_kernel<<<(B_ * S_ * 20 * 16) / 256, 256, 0, stream>>>(qkvr, fc, fs, qr, kr, qscale);
  vtrans_kernel<<<B_ * NKV * (S_ / 128), 256, 0, stream>>>(qkvr + 2560, vtb, QKVN);

  // attention: 256 blocks x 512 thr; uniform 17-tile chains per wave (k-split + pair)
  attn_kernel<<<B_ * NH * 8, 512, 0, stream>>>(qr, kr, vtb, obf);

  // output projection -> f32 d_out (256x128 tiles, 256 blocks = 1/CU)
  gemmOP<float><<<(B_ * S_ / 256) * (DIM_ / 128), 512, 0, stream>>>(obf, wob, out, B_ * S_, DIM_, DIM_);
}